// Round 5
// baseline (704.886 us; speedup 1.0000x reference)
//
#include <hip/hip_runtime.h>

#define TPB 512
#define QPT 8      // preds per thread
#define NSEG 64    // gt-dimension split
#define NROWS 32   // 8 waves * 4 sixteen-lane groups
#define SEGMAX 128 // LDS sub-tile of refs

// Order-preserving float<->uint encoding so atomicMin(uint) == float min.
__device__ __forceinline__ unsigned encf(float f) {
    unsigned u = __float_as_uint(f);
    return (u & 0x80000000u) ? ~u : (u | 0x80000000u);
}
__device__ __forceinline__ float decf(unsigned u) {
    return __uint_as_float((u & 0x80000000u) ? (u ^ 0x80000000u) : ~u);
}

// preds packed as {-2x, -2y, -2z, ||p||^2}; gts packed as {x, y, z, ||g||^2}.
__global__ void __launch_bounds__(256) pack_preds(const float* __restrict__ pts,
                                                  float4* __restrict__ out, int total) {
    int i = blockIdx.x * blockDim.x + threadIdx.x;
    if (i < total) {
        float x = pts[3 * i], y = pts[3 * i + 1], z = pts[3 * i + 2];
        out[i] = make_float4(-2.f * x, -2.f * y, -2.f * z, fmaf(x, x, fmaf(y, y, z * z)));
    }
}
__global__ void __launch_bounds__(256) pack_gts(const float* __restrict__ pts,
                                                float4* __restrict__ out, int total) {
    int i = blockIdx.x * blockDim.x + threadIdx.x;
    if (i < total) {
        float x = pts[3 * i], y = pts[3 * i + 1], z = pts[3 * i + 2];
        out[i] = make_float4(x, y, z, fmaf(x, x, fmaf(y, y, z * z)));
    }
}
__global__ void __launch_bounds__(256) init_mins(unsigned* __restrict__ u, int total) {
    int i = blockIdx.x * blockDim.x + threadIdx.x;
    if (i < total) u[i] = 0xFFFFFFFFu;  // encodes +max — identity for min
}

// Fused single pass. Grid: (qChunks, NSEG, B). d = ||g||^2 - 2 p.g computed ONCE
// per pair feeds (a) the per-pred register min and (b) the per-gt block min via
// shfl butterfly + LDS rows (NO contended global atomics — round-4 lesson:
// same-line cross-XCD atomicMin cost ~160B HBM traffic each).
__global__ void __launch_bounds__(TPB, 8) fused_chamfer(const float4* __restrict__ P4,
                                                        const float4* __restrict__ G4,
                                                        unsigned* __restrict__ upred,
                                                        float* __restrict__ gpart,
                                                        int N, int M, int B) {
    const int b     = blockIdx.z;
    const int seg   = blockIdx.y;
    const int chunk = blockIdx.x;

    const float4* __restrict__ Q = P4 + (size_t)b * N;
    const float4* __restrict__ R = G4 + (size_t)b * M;

    const int segLen = (M + NSEG - 1) / NSEG;
    const int s0 = seg * segLen;
    const int s1 = (s0 + segLen < M) ? (s0 + segLen) : M;
    if (s0 >= s1) return;

    const int lane = (int)threadIdx.x & 63;
    const int wid  = (int)threadIdx.x >> 6;
    const int row  = (wid << 2) | (lane >> 4);   // this lane's LDS row if group leader
    const int qbase = chunk * (TPB * QPT) + (int)threadIdx.x;

    float p2x[QPT], p2y[QPT], p2z[QPT], pw[QPT], m[QPT];
    #pragma unroll
    for (int j = 0; j < QPT; ++j) {
        const int q  = qbase + j * TPB;
        const int qc = (q < N) ? q : 0;  // clamped lanes duplicate pred 0: min-safe
        float4 t = Q[qc];
        p2x[j] = t.x; p2y[j] = t.y; p2z[j] = t.z; pw[j] = t.w;
        m[j] = 3.4e38f;
    }

    __shared__ float wmin[NROWS][SEGMAX + 1];  // +1 pad: leaders write conflict-free

#define PAIR(rr, jj) fmaf(p2x[jj], (rr).x, fmaf(p2y[jj], (rr).y, fmaf(p2z[jj], (rr).z, (rr).w)))

    // Per-ref: d for 8 preds; update pred mins; reduce (d+pw) over j (min3 tree)
    // then over 16 lanes (4 butterfly stages, DS pipe); leaders stash in LDS.
    auto process1 = [&](const float4& r, int col) {
        float d[QPT];
        #pragma unroll
        for (int j = 0; j < QPT; ++j) d[j] = PAIR(r, j);
        m[0] = fminf(fminf(m[0], d[0]), d[1] < d[2] ? d[1] : d[2]);  // keep simple: see below
        // (pred-side mins done properly in caller for the 4-wide path)
        float e0 = d[0] + pw[0], e1 = d[1] + pw[1], e2 = d[2] + pw[2], e3 = d[3] + pw[3];
        float e4 = d[4] + pw[4], e5 = d[5] + pw[5], e6 = d[6] + pw[6], e7 = d[7] + pw[7];
        float a = fminf(fminf(e0, e1), e2);
        float bb = fminf(fminf(e3, e4), e5);
        float t = fminf(fminf(a, bb), e6);
        t = fminf(t, e7);
        t = fminf(t, __shfl_xor(t, 1));
        t = fminf(t, __shfl_xor(t, 2));
        t = fminf(t, __shfl_xor(t, 4));
        t = fminf(t, __shfl_xor(t, 8));
        if ((lane & 15) == 0) wmin[row][col] = t;
        #pragma unroll
        for (int j = 1; j < QPT; ++j) m[j] = fminf(m[j], d[j]);  // fix pred mins (j0 above)
    };

    for (int t0 = s0; t0 < s1; t0 += SEGMAX) {
        const int t1 = (t0 + SEGMAX < s1) ? (t0 + SEGMAX) : s1;

        int i = t0;
        if (t1 - t0 >= 8) {
            float4 r0 = R[i + 0], r1 = R[i + 1], r2 = R[i + 2], r3 = R[i + 3];
            for (; i + 8 <= t1; i += 4) {
                float4 n0 = R[i + 4], n1 = R[i + 5], n2 = R[i + 6], n3 = R[i + 7];
                float d0[QPT], d1[QPT], d2[QPT], d3[QPT];
                #pragma unroll
                for (int j = 0; j < QPT; ++j) {
                    d0[j] = PAIR(r0, j);
                    d1[j] = PAIR(r1, j);
                    d2[j] = PAIR(r2, j);
                    d3[j] = PAIR(r3, j);
                    m[j] = fminf(fminf(m[j], d0[j]), d1[j]);  // -> v_min3_f32
                    m[j] = fminf(fminf(m[j], d2[j]), d3[j]);
                }
                #pragma unroll
                for (int k = 0; k < 4; ++k) {
                    const float* d = (k == 0) ? d0 : (k == 1) ? d1 : (k == 2) ? d2 : d3;
                    float e0 = d[0] + pw[0], e1 = d[1] + pw[1], e2 = d[2] + pw[2], e3 = d[3] + pw[3];
                    float e4 = d[4] + pw[4], e5 = d[5] + pw[5], e6 = d[6] + pw[6], e7 = d[7] + pw[7];
                    float a = fminf(fminf(e0, e1), e2);
                    float bb = fminf(fminf(e3, e4), e5);
                    float t = fminf(fminf(a, bb), e6);
                    t = fminf(t, e7);
                    t = fminf(t, __shfl_xor(t, 1));
                    t = fminf(t, __shfl_xor(t, 2));
                    t = fminf(t, __shfl_xor(t, 4));
                    t = fminf(t, __shfl_xor(t, 8));
                    if ((lane & 15) == 0) wmin[row][(i - t0) + k] = t;
                }
                r0 = n0; r1 = n1; r2 = n2; r3 = n3;
            }
            // drain the last prefetched quad
            {
                float d0[QPT], d1[QPT], d2[QPT], d3[QPT];
                #pragma unroll
                for (int j = 0; j < QPT; ++j) {
                    d0[j] = PAIR(r0, j);
                    d1[j] = PAIR(r1, j);
                    d2[j] = PAIR(r2, j);
                    d3[j] = PAIR(r3, j);
                    m[j] = fminf(fminf(m[j], d0[j]), d1[j]);
                    m[j] = fminf(fminf(m[j], d2[j]), d3[j]);
                }
                #pragma unroll
                for (int k = 0; k < 4; ++k) {
                    const float* d = (k == 0) ? d0 : (k == 1) ? d1 : (k == 2) ? d2 : d3;
                    float e0 = d[0] + pw[0], e1 = d[1] + pw[1], e2 = d[2] + pw[2], e3 = d[3] + pw[3];
                    float e4 = d[4] + pw[4], e5 = d[5] + pw[5], e6 = d[6] + pw[6], e7 = d[7] + pw[7];
                    float a = fminf(fminf(e0, e1), e2);
                    float bb = fminf(fminf(e3, e4), e5);
                    float t = fminf(fminf(a, bb), e6);
                    t = fminf(t, e7);
                    t = fminf(t, __shfl_xor(t, 1));
                    t = fminf(t, __shfl_xor(t, 2));
                    t = fminf(t, __shfl_xor(t, 4));
                    t = fminf(t, __shfl_xor(t, 8));
                    if ((lane & 15) == 0) wmin[row][(i - t0) + k] = t;
                }
                i += 4;
            }
        }
        for (; i < t1; ++i) {
            float4 r = R[i];
            process1(r, i - t0);
        }

        __syncthreads();
        // Min the 32 rows, write per-chunk partial (disjoint slices: no atomics).
        float* __restrict__ gdst = gpart + ((size_t)chunk * B + b) * M;
        for (int idx = (int)threadIdx.x; idx < t1 - t0; idx += TPB) {
            float v = wmin[0][idx];
            #pragma unroll
            for (int r = 1; r < NROWS; ++r) v = fminf(v, wmin[r][idx]);
            gdst[t0 + idx] = v;
        }
        __syncthreads();
    }
#undef PAIR

    // Pred-side: low-contention atomics (round-3-proven: ~4B HBM each).
    unsigned* __restrict__ pdst = upred + (size_t)b * N;
    #pragma unroll
    for (int j = 0; j < QPT; ++j) {
        const int q = qbase + j * TPB;
        if (q < N) atomicMin(&pdst[q], encf(m[j] + pw[j]));
    }
}

// One block per batch: decode pred mins; min gt partials across chunks; sum both.
__global__ void __launch_bounds__(256) finish(const unsigned* __restrict__ upred,
                                              const float* __restrict__ gpart,
                                              float* __restrict__ out,
                                              int N, int M, int B, int qChunks) {
    const int b = blockIdx.x;
    const unsigned* m0 = upred + (size_t)b * N;

    float s0 = 0.f, s1 = 0.f;
    for (int q = (int)threadIdx.x; q < N; q += 256) s0 += decf(m0[q]);
    for (int g = (int)threadIdx.x; g < M; g += 256) {
        float v = gpart[(size_t)b * M + g];
        for (int c = 1; c < qChunks; ++c)
            v = fminf(v, gpart[((size_t)c * B + b) * M + g]);
        s1 += v;
    }

    for (int off = 32; off > 0; off >>= 1) {
        s0 += __shfl_down(s0, off);
        s1 += __shfl_down(s1, off);
    }
    __shared__ float r0s[4], r1s[4];
    const int wid  = (int)threadIdx.x >> 6;
    const int lane = (int)threadIdx.x & 63;
    if (lane == 0) { r0s[wid] = s0; r1s[wid] = s1; }
    __syncthreads();
    if (threadIdx.x == 0) {
        float S0 = 0.f, S1 = 0.f;
        #pragma unroll
        for (int w = 0; w < 4; ++w) { S0 += r0s[w]; S1 += r1s[w]; }
        out[b] = S0 / (float)N + S1 / (float)M;
    }
}

extern "C" void kernel_launch(void* const* d_in, const int* in_sizes, int n_in,
                              void* d_out, int out_size, void* d_ws, size_t ws_size,
                              hipStream_t stream) {
    const float* preds = (const float*)d_in[0];  // [B, N, 3]
    const float* gts   = (const float*)d_in[1];  // [B, M, 3]
    float* out = (float*)d_out;                  // [B]

    const int B = out_size;                      // 8
    const int N = in_sizes[0] / (B * 3);         // 8192
    const int M = in_sizes[1] / (B * 3);         // 8192
    const int qChunks = (N + TPB * QPT - 1) / (TPB * QPT);  // 2

    float4*   P4    = (float4*)d_ws;                    // [B*N]
    float4*   G4    = P4 + (size_t)B * N;               // [B*M]
    unsigned* upred = (unsigned*)(G4 + (size_t)B * M);  // [B*N]
    float*    gpart = (float*)(upred + (size_t)B * N);  // [qChunks][B][M]

    const int totalP = B * N;
    const int totalG = B * M;
    pack_preds<<<(totalP + 255) / 256, 256, 0, stream>>>(preds, P4, totalP);
    pack_gts<<<(totalG + 255) / 256, 256, 0, stream>>>(gts, G4, totalG);
    init_mins<<<(totalP + 255) / 256, 256, 0, stream>>>(upred, totalP);

    dim3 grid(qChunks, NSEG, B);
    fused_chamfer<<<grid, TPB, 0, stream>>>(P4, G4, upred, gpart, N, M, B);

    finish<<<B, 256, 0, stream>>>(upred, gpart, out, N, M, B, qChunks);
}

// Round 6
// 126.003 us; speedup vs baseline: 5.5942x; 5.5942x over previous
//
#include <hip/hip_runtime.h>

#define TPB 512
#define QPT 8    // queries per thread
#define NSEG 32  // ref-dimension split

// Order-preserving float<->uint encoding so atomicMin(uint) == float min.
__device__ __forceinline__ unsigned encf(float f) {
    unsigned u = __float_as_uint(f);
    return (u & 0x80000000u) ? ~u : (u | 0x80000000u);
}
__device__ __forceinline__ float decf(unsigned u) {
    return __uint_as_float((u & 0x80000000u) ? (u ^ 0x80000000u) : ~u);
}

// Fused prep: pack preds+gts into float4 {x,y,z,||.||^2}; init umins to +max.
__global__ void __launch_bounds__(256) prep(const float* __restrict__ preds,
                                            const float* __restrict__ gts,
                                            float4* __restrict__ P4,
                                            float4* __restrict__ G4,
                                            unsigned* __restrict__ umins,
                                            int totalP, int totalG, int totalU) {
    int i = blockIdx.x * blockDim.x + threadIdx.x;
    if (i < totalP) {
        float x = preds[3 * i], y = preds[3 * i + 1], z = preds[3 * i + 2];
        P4[i] = make_float4(x, y, z, fmaf(x, x, fmaf(y, y, z * z)));
    } else if (i < totalP + totalG) {
        int k = i - totalP;
        float x = gts[3 * k], y = gts[3 * k + 1], z = gts[3 * k + 2];
        G4[k] = make_float4(x, y, z, fmaf(x, x, fmaf(y, y, z * z)));
    }
    if (i < totalU) umins[i] = 0xFFFFFFFFu;  // encodes +max — identity for min
}

// Round-3 structure (proven no-spill: refs ride SGPRs via uniform s_loads,
// per-lane state ~40 VGPR < 64 cap). Grid: (qChunks, NSEG, 2*B).
// Each thread owns QPT queries; scans one ref segment with 1-quad prefetch.
// Output: atomicMin of per-query segment min (low contention: ~4B HBM each).
__global__ void __launch_bounds__(TPB, 8) chamfer_dir(const float4* __restrict__ P4,
                                                      const float4* __restrict__ G4,
                                                      unsigned* __restrict__ umins,
                                                      int N, int M, int B, int nQpad) {
    const int db  = blockIdx.z;          // dir*B + b
    const int dir = db / B;
    const int b   = db - dir * B;
    const int seg = blockIdx.y;

    const float4* __restrict__ Q = (dir == 0) ? (P4 + (size_t)b * N) : (G4 + (size_t)b * M);
    const float4* __restrict__ R = (dir == 0) ? (G4 + (size_t)b * M) : (P4 + (size_t)b * N);
    const int nQ = (dir == 0) ? N : M;
    const int nR = (dir == 0) ? M : N;

    const int segLen = (nR + NSEG - 1) / NSEG;
    const int s0 = seg * segLen;
    const int s1 = (s0 + segLen < nR) ? (s0 + segLen) : nR;
    if (s0 >= s1) return;

    const int qbase = blockIdx.x * (TPB * QPT) + (int)threadIdx.x;

    float q2x[QPT], q2y[QPT], q2z[QPT], qw[QPT], m[QPT];
    #pragma unroll
    for (int j = 0; j < QPT; ++j) {
        const int q  = qbase + j * TPB;
        const int qc = (q < nQ) ? q : 0;   // clamp; guarded at the atomic
        float4 t = Q[qc];
        q2x[j] = -2.f * t.x;
        q2y[j] = -2.f * t.y;
        q2z[j] = -2.f * t.z;
        qw[j]  = t.w;
        m[j]   = 3.4e38f;
    }

#define PAIR(rr, jj)  fmaf(q2x[jj], (rr).x, fmaf(q2y[jj], (rr).y, fmaf(q2z[jj], (rr).z, (rr).w)))

    int i = s0;
    if (s1 - s0 >= 8) {
        float4 r0 = R[i + 0], r1 = R[i + 1], r2 = R[i + 2], r3 = R[i + 3];
        for (; i + 8 <= s1; i += 4) {
            // Prefetch next 64B (uniform -> s_load quads, SGPR-resident).
            float4 n0 = R[i + 4], n1 = R[i + 5], n2 = R[i + 6], n3 = R[i + 7];
            #pragma unroll
            for (int j = 0; j < QPT; ++j) {
                float d0 = PAIR(r0, j);
                float d1 = PAIR(r1, j);
                float d2 = PAIR(r2, j);
                float d3 = PAIR(r3, j);
                m[j] = fminf(fminf(m[j], d0), d1);   // -> v_min3_f32
                m[j] = fminf(fminf(m[j], d2), d3);   // -> v_min3_f32
            }
            r0 = n0; r1 = n1; r2 = n2; r3 = n3;
        }
        #pragma unroll
        for (int j = 0; j < QPT; ++j) {
            float d0 = PAIR(r0, j);
            float d1 = PAIR(r1, j);
            float d2 = PAIR(r2, j);
            float d3 = PAIR(r3, j);
            m[j] = fminf(fminf(m[j], d0), d1);
            m[j] = fminf(fminf(m[j], d2), d3);
        }
        i += 4;
    }
    for (; i < s1; ++i) {
        float4 r = R[i];
        #pragma unroll
        for (int j = 0; j < QPT; ++j) m[j] = fminf(m[j], PAIR(r, j));
    }
#undef PAIR

    unsigned* dst = umins + (size_t)db * nQpad;
    #pragma unroll
    for (int j = 0; j < QPT; ++j) {
        const int q = qbase + j * TPB;
        if (q < nQ) atomicMin(&dst[q], encf(m[j] + qw[j]));
    }
}

// One block per batch b: decode + fixed-order sums for both directions.
__global__ void __launch_bounds__(256) finish(const unsigned* __restrict__ umins,
                                              float* __restrict__ out,
                                              int N, int M, int B, int nQpad) {
    const int b = blockIdx.x;
    const unsigned* m0 = umins + (size_t)b * nQpad;            // dir 0 (per-pred)
    const unsigned* m1 = umins + (size_t)(B + b) * nQpad;      // dir 1 (per-gt)

    float s0 = 0.f, s1 = 0.f;
    for (int q = (int)threadIdx.x; q < N; q += 256) s0 += decf(m0[q]);
    for (int q = (int)threadIdx.x; q < M; q += 256) s1 += decf(m1[q]);

    for (int off = 32; off > 0; off >>= 1) {
        s0 += __shfl_down(s0, off);
        s1 += __shfl_down(s1, off);
    }
    __shared__ float r0s[4], r1s[4];
    const int wid  = (int)threadIdx.x >> 6;
    const int lane = (int)threadIdx.x & 63;
    if (lane == 0) { r0s[wid] = s0; r1s[wid] = s1; }
    __syncthreads();
    if (threadIdx.x == 0) {
        float S0 = 0.f, S1 = 0.f;
        #pragma unroll
        for (int w = 0; w < 4; ++w) { S0 += r0s[w]; S1 += r1s[w]; }
        out[b] = S0 / (float)N + S1 / (float)M;
    }
}

extern "C" void kernel_launch(void* const* d_in, const int* in_sizes, int n_in,
                              void* d_out, int out_size, void* d_ws, size_t ws_size,
                              hipStream_t stream) {
    const float* preds = (const float*)d_in[0];  // [B, N, 3]
    const float* gts   = (const float*)d_in[1];  // [B, M, 3]
    float* out = (float*)d_out;                  // [B]

    const int B = out_size;                      // 8
    const int N = in_sizes[0] / (B * 3);         // 8192
    const int M = in_sizes[1] / (B * 3);         // 8192
    const int nQpad = (N > M ? N : M);

    float4*   P4    = (float4*)d_ws;             // [B*N]
    float4*   G4    = P4 + (size_t)B * N;        // [B*M]
    unsigned* umins = (unsigned*)(G4 + (size_t)B * M);  // [2*B][nQpad]

    const int totalP = B * N;
    const int totalG = B * M;
    const int totalU = 2 * B * nQpad;
    const int prepTot = (totalP + totalG > totalU) ? (totalP + totalG) : totalU;
    prep<<<(prepTot + 255) / 256, 256, 0, stream>>>(preds, gts, P4, G4, umins,
                                                    totalP, totalG, totalU);

    const int qChunks = (nQpad + TPB * QPT - 1) / (TPB * QPT);  // 2
    dim3 grid(qChunks, NSEG, 2 * B);                            // 2*32*16 = 1024
    chamfer_dir<<<grid, TPB, 0, stream>>>(P4, G4, umins, N, M, B, nQpad);

    finish<<<B, 256, 0, stream>>>(umins, out, N, M, B, nQpad);
}

// Round 7
// 107.649 us; speedup vs baseline: 6.5480x; 1.1705x over previous
//
#include <hip/hip_runtime.h>

#define TPB 512
#define QPT 8            // queries per thread = 4 packed chains
#define NCH (QPT / 2)
#define NSEG 32          // ref-dimension split

typedef float v2f __attribute__((ext_vector_type(2)));

// Refs stored pre-duplicated: {x,x},{y,y},{z,z},{w,w} — each double is an
// SGPR-pair broadcast operand for VOP3P packed math (1 scalar operand/instr).
struct RefDup { double x2, y2, z2, w2; };

// Order-preserving float<->uint encoding so atomicMin(uint) == float min.
__device__ __forceinline__ unsigned encf(float f) {
    unsigned u = __float_as_uint(f);
    return (u & 0x80000000u) ? ~u : (u | 0x80000000u);
}
__device__ __forceinline__ float decf(unsigned u) {
    return __uint_as_float((u & 0x80000000u) ? (u ^ 0x80000000u) : ~u);
}
__device__ __forceinline__ double dup2(float v) {
    union { float f[2]; double d; } u; u.f[0] = v; u.f[1] = v; return u.d;
}

// v_pk_fma_f32: D = S0*S1 + S2 per 32-bit half. S1 is the wave-uniform ref
// component (SGPR pair {c,c} -> broadcast); S0/S2 are per-lane VGPR pairs.
__device__ __forceinline__ v2f pk_fma_vs(v2f a, double b, v2f c) {
    v2f d; asm("v_pk_fma_f32 %0, %1, %2, %3" : "=v"(d) : "v"(a), "s"(b), "v"(c)); return d;
}

// Pack both inputs into duplicated layout; init umins to +max.
__global__ void __launch_bounds__(256) prep(const float* __restrict__ preds,
                                            const float* __restrict__ gts,
                                            RefDup* __restrict__ P8,
                                            RefDup* __restrict__ G8,
                                            unsigned* __restrict__ umins,
                                            int totalP, int totalG, int totalU) {
    int i = blockIdx.x * blockDim.x + threadIdx.x;
    if (i < totalP) {
        float x = preds[3 * i], y = preds[3 * i + 1], z = preds[3 * i + 2];
        RefDup r;
        r.x2 = dup2(x); r.y2 = dup2(y); r.z2 = dup2(z);
        r.w2 = dup2(fmaf(x, x, fmaf(y, y, z * z)));
        P8[i] = r;
    } else if (i < totalP + totalG) {
        int k = i - totalP;
        float x = gts[3 * k], y = gts[3 * k + 1], z = gts[3 * k + 2];
        RefDup r;
        r.x2 = dup2(x); r.y2 = dup2(y); r.z2 = dup2(z);
        r.w2 = dup2(fmaf(x, x, fmaf(y, y, z * z)));
        G8[k] = r;
    }
    if (i < totalU) umins[i] = 0xFFFFFFFFu;  // encodes +max — identity for min
}

// Grid: (qChunks, NSEG, 2*B). Each thread owns QPT queries as NCH packed
// pairs; refs stream via uniform s_load (SGPR-resident), prefetch depth 4.
// Per pair: 1.5 pk_fma + 0.5 min3 + 0.25 mov = 2.25 VALU instrs.
__global__ void __launch_bounds__(TPB, 4) chamfer_dir(const RefDup* __restrict__ P8,
                                                      const RefDup* __restrict__ G8,
                                                      unsigned* __restrict__ umins,
                                                      int N, int M, int B, int nQpad) {
    const int db  = blockIdx.z;          // dir*B + b
    const int dir = db / B;
    const int b   = db - dir * B;
    const int seg = blockIdx.y;

    const RefDup* __restrict__ Qd = (dir == 0) ? (P8 + (size_t)b * N) : (G8 + (size_t)b * M);
    const RefDup* __restrict__ R  = (dir == 0) ? (G8 + (size_t)b * M) : (P8 + (size_t)b * N);
    const int nQ = (dir == 0) ? N : M;
    const int nR = (dir == 0) ? M : N;

    const int segLen = (nR + NSEG - 1) / NSEG;
    const int s0 = seg * segLen;
    const int s1 = (s0 + segLen < nR) ? (s0 + segLen) : nR;
    if (s0 >= s1) return;

    const int qbase = blockIdx.x * (TPB * QPT) + (int)threadIdx.x;

    // Query state: chain c holds queries (qbase+2c*TPB, qbase+(2c+1)*TPB) in
    // lo/hi halves. Coordinates pre-scaled by -2 so d = fma-chain ending in w.
    v2f qx2[NCH], qy2[NCH], qz2[NCH], pw2[NCH], m2[NCH];
    #pragma unroll
    for (int c = 0; c < NCH; ++c) {
        const int qa = qbase + (2 * c) * TPB;
        const int qb = qbase + (2 * c + 1) * TPB;
        const int qac = (qa < nQ) ? qa : 0;   // clamp; guarded at the atomic
        const int qbc = (qb < nQ) ? qb : 0;
        const float* fa = (const float*)&Qd[qac];  // {x,x,y,y,z,z,w,w}
        const float* fb = (const float*)&Qd[qbc];
        qx2[c].x = -2.f * fa[0]; qx2[c].y = -2.f * fb[0];
        qy2[c].x = -2.f * fa[2]; qy2[c].y = -2.f * fb[2];
        qz2[c].x = -2.f * fa[4]; qz2[c].y = -2.f * fb[4];
        pw2[c].x = fa[6];        pw2[c].y = fb[6];
        m2[c].x = 3.4e38f;       m2[c].y = 3.4e38f;
    }

    // w duplicated into a VGPR pair once per ref (shared by all chains) so the
    // innermost pk_fma has only ONE scalar operand (the z-component pair).
    auto dupw = [](double w) -> v2f {
        union { double d; float f[2]; } u; u.d = w;
        v2f r; r.x = u.f[0]; r.y = u.f[1]; return r;
    };

    auto step4 = [&](const RefDup& r0, const RefDup& r1,
                     const RefDup& r2, const RefDup& r3) {
        v2f w0 = dupw(r0.w2), w1 = dupw(r1.w2), w2v = dupw(r2.w2), w3 = dupw(r3.w2);
        #pragma unroll
        for (int c = 0; c < NCH; ++c) {
            v2f d0 = pk_fma_vs(qz2[c], r0.z2, w0);
            d0 = pk_fma_vs(qy2[c], r0.y2, d0);
            d0 = pk_fma_vs(qx2[c], r0.x2, d0);
            v2f d1 = pk_fma_vs(qz2[c], r1.z2, w1);
            d1 = pk_fma_vs(qy2[c], r1.y2, d1);
            d1 = pk_fma_vs(qx2[c], r1.x2, d1);
            v2f d2 = pk_fma_vs(qz2[c], r2.z2, w2v);
            d2 = pk_fma_vs(qy2[c], r2.y2, d2);
            d2 = pk_fma_vs(qx2[c], r2.x2, d2);
            v2f d3 = pk_fma_vs(qz2[c], r3.z2, w3);
            d3 = pk_fma_vs(qy2[c], r3.y2, d3);
            d3 = pk_fma_vs(qx2[c], r3.x2, d3);
            m2[c].x = fminf(fminf(m2[c].x, d0.x), d1.x);  // -> v_min3_f32
            m2[c].y = fminf(fminf(m2[c].y, d0.y), d1.y);
            m2[c].x = fminf(fminf(m2[c].x, d2.x), d3.x);
            m2[c].y = fminf(fminf(m2[c].y, d2.y), d3.y);
        }
    };

    int i = s0;
    if (s1 - s0 >= 8) {
        RefDup r0 = R[i], r1 = R[i + 1], r2 = R[i + 2], r3 = R[i + 3];
        for (; i + 8 <= s1; i += 4) {
            // Prefetch next 4 refs (uniform -> s_load_dwordx8, SGPR-resident).
            RefDup n0 = R[i + 4], n1 = R[i + 5], n2 = R[i + 6], n3 = R[i + 7];
            step4(r0, r1, r2, r3);
            r0 = n0; r1 = n1; r2 = n2; r3 = n3;
        }
        step4(r0, r1, r2, r3);
        i += 4;
    }
    for (; i < s1; ++i) {
        RefDup r = R[i];
        v2f wv = dupw(r.w2);
        #pragma unroll
        for (int c = 0; c < NCH; ++c) {
            v2f d = pk_fma_vs(qz2[c], r.z2, wv);
            d = pk_fma_vs(qy2[c], r.y2, d);
            d = pk_fma_vs(qx2[c], r.x2, d);
            m2[c].x = fminf(m2[c].x, d.x);
            m2[c].y = fminf(m2[c].y, d.y);
        }
    }

    // Low-contention atomics (proven ~4B HBM each, 16MB total).
    unsigned* __restrict__ dst = umins + (size_t)db * nQpad;
    #pragma unroll
    for (int c = 0; c < NCH; ++c) {
        const int qa = qbase + (2 * c) * TPB;
        const int qb = qbase + (2 * c + 1) * TPB;
        if (qa < nQ) atomicMin(&dst[qa], encf(m2[c].x + pw2[c].x));
        if (qb < nQ) atomicMin(&dst[qb], encf(m2[c].y + pw2[c].y));
    }
}

// One block per batch b: decode + fixed-order sums for both directions.
__global__ void __launch_bounds__(256) finish(const unsigned* __restrict__ umins,
                                              float* __restrict__ out,
                                              int N, int M, int B, int nQpad) {
    const int b = blockIdx.x;
    const unsigned* m0 = umins + (size_t)b * nQpad;            // dir 0 (per-pred)
    const unsigned* m1 = umins + (size_t)(B + b) * nQpad;      // dir 1 (per-gt)

    float s0 = 0.f, s1 = 0.f;
    for (int q = (int)threadIdx.x; q < N; q += 256) s0 += decf(m0[q]);
    for (int q = (int)threadIdx.x; q < M; q += 256) s1 += decf(m1[q]);

    for (int off = 32; off > 0; off >>= 1) {
        s0 += __shfl_down(s0, off);
        s1 += __shfl_down(s1, off);
    }
    __shared__ float r0s[4], r1s[4];
    const int wid  = (int)threadIdx.x >> 6;
    const int lane = (int)threadIdx.x & 63;
    if (lane == 0) { r0s[wid] = s0; r1s[wid] = s1; }
    __syncthreads();
    if (threadIdx.x == 0) {
        float S0 = 0.f, S1 = 0.f;
        #pragma unroll
        for (int w = 0; w < 4; ++w) { S0 += r0s[w]; S1 += r1s[w]; }
        out[b] = S0 / (float)N + S1 / (float)M;
    }
}

extern "C" void kernel_launch(void* const* d_in, const int* in_sizes, int n_in,
                              void* d_out, int out_size, void* d_ws, size_t ws_size,
                              hipStream_t stream) {
    const float* preds = (const float*)d_in[0];  // [B, N, 3]
    const float* gts   = (const float*)d_in[1];  // [B, M, 3]
    float* out = (float*)d_out;                  // [B]

    const int B = out_size;                      // 8
    const int N = in_sizes[0] / (B * 3);         // 8192
    const int M = in_sizes[1] / (B * 3);         // 8192
    const int nQpad = (N > M ? N : M);

    RefDup*   P8    = (RefDup*)d_ws;                     // [B*N]  (32 B each)
    RefDup*   G8    = P8 + (size_t)B * N;                // [B*M]
    unsigned* umins = (unsigned*)(G8 + (size_t)B * M);   // [2*B][nQpad]

    const int totalP = B * N;
    const int totalG = B * M;
    const int totalU = 2 * B * nQpad;
    const int prepTot = (totalP + totalG > totalU) ? (totalP + totalG) : totalU;
    prep<<<(prepTot + 255) / 256, 256, 0, stream>>>(preds, gts, P8, G8, umins,
                                                    totalP, totalG, totalU);

    const int qChunks = (nQpad + TPB * QPT - 1) / (TPB * QPT);  // 2
    dim3 grid(qChunks, NSEG, 2 * B);                            // 2*32*16 = 1024
    chamfer_dir<<<grid, TPB, 0, stream>>>(P8, G8, umins, N, M, B, nQpad);

    finish<<<B, 256, 0, stream>>>(umins, out, N, M, B, nQpad);
}